// Round 1
// baseline (1245.341 us; speedup 1.0000x reference)
//
#include <hip/hip_runtime.h>
#include <hip/hip_bf16.h>
#include <math.h>

// Problem constants
#define HD 1024     // hidden H
#define ID 512      // moe intermediate I
#define NE 32       // n experts
#define NT 2048     // tokens T = B*S
#define NG 4        // n_group
#define SHI 1024    // shared intermediate I*N_SHARED
#define SCALE 2.5f

// GEMM tile params
#define TM 64
#define TN 64
#define KT 32

// ---------------- zero counts ----------------
__global__ void zero_counts_kernel(int* counts) {
    if (threadIdx.x < NE) counts[threadIdx.x] = 0;
}

// ---------------- router ----------------
__global__ void __launch_bounds__(64) router_kernel(
    const float* __restrict__ hs, const float* __restrict__ rw,
    const float* __restrict__ rb, float* __restrict__ topkw,
    int* __restrict__ counts, int* __restrict__ lists)
{
    int t = blockIdx.x;
    int lane = threadIdx.x;  // 64 threads = 1 wave
    __shared__ float sc[NE];
    const float* x = hs + (size_t)t * HD;
    for (int e = 0; e < NE; ++e) {
        float p = 0.f;
        const float* w = rw + (size_t)e * HD;
        for (int h = lane; h < HD; h += 64) p += x[h] * w[h];
        #pragma unroll
        for (int off = 32; off > 0; off >>= 1) p += __shfl_down(p, off);
        if (lane == 0) sc[e] = 1.f / (1.f + __expf(-p));
    }
    __syncthreads();
    if (lane == 0) {
        float scores[NE], sfc[NE], tmp[NE];
        for (int e = 0; e < NE; ++e) { scores[e] = sc[e]; sfc[e] = sc[e] + rb[e]; }
        // group scores = sum of top-2 per group of 8
        float gs[NG];
        for (int g = 0; g < NG; ++g) {
            float m1 = -1e30f, m2 = -1e30f;
            for (int j = 0; j < 8; ++j) {
                float v = sfc[g * 8 + j];
                if (v > m1) { m2 = m1; m1 = v; } else if (v > m2) m2 = v;
            }
            gs[g] = m1 + m2;
        }
        // top-2 groups (first-occurrence tie-break like lax.top_k)
        int g1 = 0;
        for (int g = 1; g < NG; ++g) if (gs[g] > gs[g1]) g1 = g;
        int g2 = -1;
        for (int g = 0; g < NG; ++g) {
            if (g == g1) continue;
            if (g2 < 0 || gs[g] > gs[g2]) g2 = g;
        }
        for (int e = 0; e < NE; ++e) {
            int g = e >> 3;
            tmp[e] = (g == g1 || g == g2) ? sfc[e] : 0.0f;
        }
        int idx[4]; float wk[4]; float wsum = 0.f;
        for (int k = 0; k < 4; ++k) {
            int best = 0; float bv = -1e30f;
            for (int e = 0; e < NE; ++e) if (tmp[e] > bv) { bv = tmp[e]; best = e; }
            idx[k] = best; tmp[best] = -1e30f;
            wk[k] = scores[best]; wsum += wk[k];
        }
        float inv = SCALE / (wsum + 1e-20f);
        for (int k = 0; k < 4; ++k) {
            int p = t * 4 + k;
            topkw[p] = wk[k] * inv;
            int e = idx[k];
            int pos = atomicAdd(&counts[e], 1);
            lists[e * NT + pos] = p;
        }
    }
}

// ---------------- fused gate/up + SwiGLU GEMM ----------------
// C_g[m,n] = X[tok(m),:] . Wg[n,:],  C_u likewise; Hout[p,n] = silu(g)*u
// EXPERT: Wg/Wu are [NE, NDIM, KDIM], token list per expert, Hout indexed by pair p.
// !EXPERT: dense over all tokens, Hout indexed by token.
template<bool EXPERT, int KDIM, int NDIM>
__global__ void __launch_bounds__(256) gateup_kernel(
    const float* __restrict__ X, const float* __restrict__ Wg,
    const float* __restrict__ Wu, float* __restrict__ Hout,
    const int* __restrict__ lists, const int* __restrict__ counts)
{
    int e = 0, cnt = NT;
    const float* wg = Wg; const float* wu = Wu;
    if (EXPERT) {
        e = blockIdx.x; cnt = counts[e];
        wg = Wg + (size_t)e * NDIM * KDIM;
        wu = Wu + (size_t)e * NDIM * KDIM;
    }
    int mt = blockIdx.y, nt = blockIdx.z;
    if (mt * TM >= cnt) return;

    __shared__ float Xs[KT][TM + 1];
    __shared__ float Gs[KT][TN + 1];
    __shared__ float Us[KT][TN + 1];

    int tid = threadIdx.x;
    int tx = tid & 15, ty = tid >> 4;
    float accg[4][4] = {{0}}, accu[4][4] = {{0}};

    for (int k0 = 0; k0 < KDIM; k0 += KT) {
        #pragma unroll
        for (int r = 0; r < (TM * KT) / 256; ++r) {
            int idx = r * 256 + tid;
            int m = idx >> 5, kk = idx & 31;
            int gm = mt * TM + m;
            int mm = gm < cnt ? gm : cnt - 1;
            int tok;
            if (EXPERT) tok = lists[e * NT + mm] >> 2;
            else tok = mm;
            Xs[kk][m] = X[(size_t)tok * HD + k0 + kk];
        }
        #pragma unroll
        for (int r = 0; r < (TN * KT) / 256; ++r) {
            int idx = r * 256 + tid;
            int n = idx >> 5, kk = idx & 31;
            size_t off = (size_t)(nt * TN + n) * KDIM + k0 + kk;
            Gs[kk][n] = wg[off];
            Us[kk][n] = wu[off];
        }
        __syncthreads();
        #pragma unroll 8
        for (int kk = 0; kk < KT; ++kk) {
            float a[4], bg[4], bu[4];
            #pragma unroll
            for (int i = 0; i < 4; ++i) a[i] = Xs[kk][ty * 4 + i];
            #pragma unroll
            for (int j = 0; j < 4; ++j) { bg[j] = Gs[kk][tx * 4 + j]; bu[j] = Us[kk][tx * 4 + j]; }
            #pragma unroll
            for (int i = 0; i < 4; ++i)
                #pragma unroll
                for (int j = 0; j < 4; ++j) {
                    accg[i][j] += a[i] * bg[j];
                    accu[i][j] += a[i] * bu[j];
                }
        }
        __syncthreads();
    }
    #pragma unroll
    for (int i = 0; i < 4; ++i) {
        int gm = mt * TM + ty * 4 + i;
        if (gm >= cnt) continue;
        int p;
        if (EXPERT) p = lists[e * NT + gm];
        else p = gm;
        #pragma unroll
        for (int j = 0; j < 4; ++j) {
            int gn = nt * TN + tx * 4 + j;
            float g = accg[i][j], u = accu[i][j];
            float hval = (g / (1.f + __expf(-g))) * u;
            Hout[(size_t)p * NDIM + gn] = hval;
        }
    }
}

// ---------------- down-projection GEMM ----------------
// EXPERT: out[t,n] += topkw[p] * (H[p,:] . Wd[e,n,:])   via atomicAdd
// !EXPERT: out[t,n] = H[t,:] . Wd[n,:]                  plain write (runs first)
template<bool EXPERT, int KDIM>
__global__ void __launch_bounds__(256) down_kernel(
    const float* __restrict__ Hin, const float* __restrict__ Wd,
    float* __restrict__ out, const int* __restrict__ lists,
    const int* __restrict__ counts, const float* __restrict__ topkw)
{
    int e = 0, cnt = NT;
    const float* wd = Wd;
    if (EXPERT) {
        e = blockIdx.x; cnt = counts[e];
        wd = Wd + (size_t)e * HD * KDIM;
    }
    int mt = blockIdx.y, nt = blockIdx.z;
    if (mt * TM >= cnt) return;

    __shared__ float Xs[KT][TM + 1];
    __shared__ float Ws[KT][TN + 1];

    int tid = threadIdx.x;
    int tx = tid & 15, ty = tid >> 4;
    float acc[4][4] = {{0}};

    for (int k0 = 0; k0 < KDIM; k0 += KT) {
        #pragma unroll
        for (int r = 0; r < (TM * KT) / 256; ++r) {
            int idx = r * 256 + tid;
            int m = idx >> 5, kk = idx & 31;
            int gm = mt * TM + m;
            int mm = gm < cnt ? gm : cnt - 1;
            int row;
            if (EXPERT) row = lists[e * NT + mm];   // pair index into Hin
            else row = mm;                          // token index
            Xs[kk][m] = Hin[(size_t)row * KDIM + k0 + kk];
        }
        #pragma unroll
        for (int r = 0; r < (TN * KT) / 256; ++r) {
            int idx = r * 256 + tid;
            int n = idx >> 5, kk = idx & 31;
            Ws[kk][n] = wd[(size_t)(nt * TN + n) * KDIM + k0 + kk];
        }
        __syncthreads();
        #pragma unroll 8
        for (int kk = 0; kk < KT; ++kk) {
            float a[4], b[4];
            #pragma unroll
            for (int i = 0; i < 4; ++i) a[i] = Xs[kk][ty * 4 + i];
            #pragma unroll
            for (int j = 0; j < 4; ++j) b[j] = Ws[kk][tx * 4 + j];
            #pragma unroll
            for (int i = 0; i < 4; ++i)
                #pragma unroll
                for (int j = 0; j < 4; ++j) acc[i][j] += a[i] * b[j];
        }
        __syncthreads();
    }
    #pragma unroll
    for (int i = 0; i < 4; ++i) {
        int gm = mt * TM + ty * 4 + i;
        if (gm >= cnt) continue;
        if (EXPERT) {
            int p = lists[e * NT + gm];
            int tok = p >> 2;
            float w = topkw[p];
            #pragma unroll
            for (int j = 0; j < 4; ++j) {
                int gn = nt * TN + tx * 4 + j;
                atomicAdd(&out[(size_t)tok * HD + gn], w * acc[i][j]);
            }
        } else {
            int tok = gm;
            #pragma unroll
            for (int j = 0; j < 4; ++j) {
                int gn = nt * TN + tx * 4 + j;
                out[(size_t)tok * HD + gn] = acc[i][j];
            }
        }
    }
}

extern "C" void kernel_launch(void* const* d_in, const int* in_sizes, int n_in,
                              void* d_out, int out_size, void* d_ws, size_t ws_size,
                              hipStream_t stream) {
    const float* hs  = (const float*)d_in[0];
    const float* rw  = (const float*)d_in[1];
    const float* rb  = (const float*)d_in[2];
    const float* gw  = (const float*)d_in[3];
    const float* uw  = (const float*)d_in[4];
    const float* dw  = (const float*)d_in[5];
    const float* sgw = (const float*)d_in[6];
    const float* suw = (const float*)d_in[7];
    const float* sdw = (const float*)d_in[8];
    float* out = (float*)d_out;

    // workspace layout
    char* ws = (char*)d_ws;
    int*   counts = (int*)ws;                                  // 128 B
    float* topkw  = (float*)(ws + 128);                        // 32 KB
    int*   lists  = (int*)(ws + 128 + 32768);                  // 256 KB
    float* hbuf   = (float*)(ws + 128 + 32768 + 262144);       // 16.78 MB (shared hsh overlaps; serialized on stream)

    zero_counts_kernel<<<1, 64, 0, stream>>>(counts);
    router_kernel<<<NT, 64, 0, stream>>>(hs, rw, rb, topkw, counts, lists);

    // shared expert path: hsh = silu(x@sgw^T)*(x@suw^T); out = hsh@sdw^T  (writes out)
    gateup_kernel<false, HD, SHI><<<dim3(1, NT / TM, SHI / TN), 256, 0, stream>>>(
        hs, sgw, suw, hbuf, nullptr, nullptr);
    down_kernel<false, SHI><<<dim3(1, NT / TM, HD / TN), 256, 0, stream>>>(
        hbuf, sdw, out, nullptr, nullptr, nullptr);

    // routed experts: h[p] = silu(x@gw_e^T)*(x@uw_e^T); out += w_p * h[p]@dw_e^T
    gateup_kernel<true, HD, ID><<<dim3(NE, NT / TM, ID / TN), 256, 0, stream>>>(
        hs, gw, uw, hbuf, lists, counts);
    down_kernel<true, ID><<<dim3(NE, NT / TM, HD / TN), 256, 0, stream>>>(
        hbuf, dw, out, lists, counts, topkw);
}

// Round 2
// 616.707 us; speedup vs baseline: 2.0193x; 2.0193x over previous
//
#include <hip/hip_runtime.h>
#include <hip/hip_bf16.h>
#include <math.h>

// Problem constants
#define HD 1024     // hidden H
#define ID 512      // moe intermediate I
#define NE 32       // n experts
#define NT 2048     // tokens T = B*S
#define NG 4        // n_group
#define SHI 1024    // shared intermediate I*N_SHARED
#define SCALE 2.5f

// MFMA GEMM tile params
#define BM 128
#define BN 64
#define BK 32
#define LDA 40      // LDS row stride in bf16 (32 + 8 pad -> 80B rows)

typedef __bf16 bf16_t;
typedef __attribute__((ext_vector_type(8))) __bf16 bf16x8;
typedef __attribute__((ext_vector_type(4))) __bf16 bf16x4;
typedef __attribute__((ext_vector_type(4))) float f32x4;

// ---------------- zero counts ----------------
__global__ void zero_counts_kernel(int* counts) {
    if (threadIdx.x < NE) counts[threadIdx.x] = 0;
}

// ---------------- router ----------------
__global__ void __launch_bounds__(64) router_kernel(
    const float* __restrict__ hs, const float* __restrict__ rw,
    const float* __restrict__ rb, float* __restrict__ topkw,
    int* __restrict__ counts, int* __restrict__ lists)
{
    int t = blockIdx.x;
    int lane = threadIdx.x;  // 64 threads = 1 wave
    __shared__ float sc[NE];
    const float* x = hs + (size_t)t * HD;
    for (int e = 0; e < NE; ++e) {
        float p = 0.f;
        const float* w = rw + (size_t)e * HD;
        for (int h = lane; h < HD; h += 64) p += x[h] * w[h];
        #pragma unroll
        for (int off = 32; off > 0; off >>= 1) p += __shfl_down(p, off);
        if (lane == 0) sc[e] = 1.f / (1.f + __expf(-p));
    }
    __syncthreads();
    if (lane == 0) {
        float scores[NE], sfc[NE], tmp[NE];
        for (int e = 0; e < NE; ++e) { scores[e] = sc[e]; sfc[e] = sc[e] + rb[e]; }
        float gs[NG];
        for (int g = 0; g < NG; ++g) {
            float m1 = -1e30f, m2 = -1e30f;
            for (int j = 0; j < 8; ++j) {
                float v = sfc[g * 8 + j];
                if (v > m1) { m2 = m1; m1 = v; } else if (v > m2) m2 = v;
            }
            gs[g] = m1 + m2;
        }
        int g1 = 0;
        for (int g = 1; g < NG; ++g) if (gs[g] > gs[g1]) g1 = g;
        int g2 = -1;
        for (int g = 0; g < NG; ++g) {
            if (g == g1) continue;
            if (g2 < 0 || gs[g] > gs[g2]) g2 = g;
        }
        for (int e = 0; e < NE; ++e) {
            int g = e >> 3;
            tmp[e] = (g == g1 || g == g2) ? sfc[e] : 0.0f;
        }
        int idx[4]; float wk[4]; float wsum = 0.f;
        for (int k = 0; k < 4; ++k) {
            int best = 0; float bv = -1e30f;
            for (int e = 0; e < NE; ++e) if (tmp[e] > bv) { bv = tmp[e]; best = e; }
            idx[k] = best; tmp[best] = -1e30f;
            wk[k] = scores[best]; wsum += wk[k];
        }
        float inv = SCALE / (wsum + 1e-20f);
        for (int k = 0; k < 4; ++k) {
            int p = t * 4 + k;
            topkw[p] = wk[k] * inv;
            int e = idx[k];
            int pos = atomicAdd(&counts[e], 1);
            lists[e * NT + pos] = p;
        }
    }
}

__device__ inline bf16x4 cvt4(float4 v) {
    bf16x4 r;
    r[0] = (__bf16)v.x; r[1] = (__bf16)v.y; r[2] = (__bf16)v.z; r[3] = (__bf16)v.w;
    return r;
}

// ---------------- fused gate/up + SwiGLU, bf16 MFMA ----------------
// X fp32 [tokens, HD]; Wg/Wu fp32 [(E,) ND, HD]; Hout bf16 [rows, ND]
// EXPERT: rows indexed by pair p from lists; else by token.
template<bool EXPERT, int ND>
__global__ void __launch_bounds__(256) gateup_mfma(
    const float* __restrict__ X, const float* __restrict__ Wg,
    const float* __restrict__ Wu, bf16_t* __restrict__ Hout,
    const int* __restrict__ lists, const int* __restrict__ counts)
{
    int e = 0, cnt = NT;
    const float* wg = Wg; const float* wu = Wu;
    if (EXPERT) {
        e = blockIdx.x; cnt = counts[e];
        wg = Wg + (size_t)e * ND * HD;
        wu = Wu + (size_t)e * ND * HD;
    }
    int mtb = blockIdx.y, ntb = blockIdx.z;
    if (mtb * BM >= cnt) return;

    __shared__ __align__(16) bf16_t As[BM * LDA];
    __shared__ __align__(16) bf16_t Bgs[BN * LDA];
    __shared__ __align__(16) bf16_t Bus[BN * LDA];
    __shared__ int rowid[BM];

    int tid = threadIdx.x;
    if (tid < BM) {
        int gm = mtb * BM + tid;
        int mm = gm < cnt ? gm : cnt - 1;
        rowid[tid] = EXPERT ? lists[e * NT + mm] : mm;
    }
    __syncthreads();

    int lane = tid & 63;
    int w = tid >> 6;
    int wm = w & 1, wn = w >> 1;
    int lrow = lane & 15, quad = lane >> 4;

    f32x4 accg[4][2], accu[4][2];
    #pragma unroll
    for (int i = 0; i < 4; ++i)
        #pragma unroll
        for (int j = 0; j < 2; ++j) { accg[i][j] = (f32x4){0,0,0,0}; accu[i][j] = (f32x4){0,0,0,0}; }

    for (int k0 = 0; k0 < HD; k0 += BK) {
        // stage A: 128 rows x 32 fp32 -> bf16
        #pragma unroll
        for (int r = 0; r < (BM * (BK / 4)) / 256; ++r) {
            int idx = r * 256 + tid;
            int row = idx >> 3, kq = idx & 7;
            int tok = EXPERT ? (rowid[row] >> 2) : rowid[row];
            float4 v = *(const float4*)(X + (size_t)tok * HD + k0 + kq * 4);
            *(bf16x4*)(As + row * LDA + kq * 4) = cvt4(v);
        }
        // stage Bg, Bu: 64 rows x 32 fp32 each
        #pragma unroll
        for (int r = 0; r < (BN * (BK / 4)) / 256; ++r) {
            int idx = r * 256 + tid;
            int n = idx >> 3, kq = idx & 7;
            size_t off = (size_t)(ntb * BN + n) * HD + k0 + kq * 4;
            *(bf16x4*)(Bgs + n * LDA + kq * 4) = cvt4(*(const float4*)(wg + off));
            *(bf16x4*)(Bus + n * LDA + kq * 4) = cvt4(*(const float4*)(wu + off));
        }
        __syncthreads();

        bf16x8 af[4], bg[2], bu[2];
        #pragma unroll
        for (int mt = 0; mt < 4; ++mt)
            af[mt] = *(const bf16x8*)(As + (wm * 64 + mt * 16 + lrow) * LDA + quad * 8);
        #pragma unroll
        for (int nt = 0; nt < 2; ++nt) {
            bg[nt] = *(const bf16x8*)(Bgs + (wn * 32 + nt * 16 + lrow) * LDA + quad * 8);
            bu[nt] = *(const bf16x8*)(Bus + (wn * 32 + nt * 16 + lrow) * LDA + quad * 8);
        }
        #pragma unroll
        for (int mt = 0; mt < 4; ++mt)
            #pragma unroll
            for (int nt = 0; nt < 2; ++nt) {
                accg[mt][nt] = __builtin_amdgcn_mfma_f32_16x16x32_bf16(af[mt], bg[nt], accg[mt][nt], 0, 0, 0);
                accu[mt][nt] = __builtin_amdgcn_mfma_f32_16x16x32_bf16(af[mt], bu[nt], accu[mt][nt], 0, 0, 0);
            }
        __syncthreads();
    }

    // epilogue: h = silu(g)*u, store bf16
    #pragma unroll
    for (int mt = 0; mt < 4; ++mt)
        #pragma unroll
        for (int r = 0; r < 4; ++r) {
            int row_local = wm * 64 + mt * 16 + quad * 4 + r;
            int gm = mtb * BM + row_local;
            if (gm >= cnt) continue;
            int p = rowid[row_local];
            #pragma unroll
            for (int nt = 0; nt < 2; ++nt) {
                int col = ntb * BN + wn * 32 + nt * 16 + lrow;
                float g = accg[mt][nt][r], u = accu[mt][nt][r];
                float h = (g / (1.f + __expf(-g))) * u;
                Hout[(size_t)p * ND + col] = (__bf16)h;
            }
        }
}

// ---------------- down projection, bf16 MFMA ----------------
// Hin bf16 [rows, KD]; Wd fp32 [(E,) HD, KD]; out fp32 [NT, HD]
// EXPERT: atomicAdd(w_p * val); else plain store (must run first).
template<bool EXPERT, int KD>
__global__ void __launch_bounds__(256) down_mfma(
    const bf16_t* __restrict__ Hin, const float* __restrict__ Wd,
    float* __restrict__ out, const int* __restrict__ lists,
    const int* __restrict__ counts, const float* __restrict__ topkw)
{
    int e = 0, cnt = NT;
    const float* wd = Wd;
    if (EXPERT) {
        e = blockIdx.x; cnt = counts[e];
        wd = Wd + (size_t)e * HD * KD;
    }
    int mtb = blockIdx.y, ntb = blockIdx.z;
    if (mtb * BM >= cnt) return;

    __shared__ __align__(16) bf16_t As[BM * LDA];
    __shared__ __align__(16) bf16_t Ws[BN * LDA];
    __shared__ int rowid[BM];

    int tid = threadIdx.x;
    if (tid < BM) {
        int gm = mtb * BM + tid;
        int mm = gm < cnt ? gm : cnt - 1;
        rowid[tid] = EXPERT ? lists[e * NT + mm] : mm;
    }
    __syncthreads();

    int lane = tid & 63;
    int w = tid >> 6;
    int wm = w & 1, wn = w >> 1;
    int lrow = lane & 15, quad = lane >> 4;

    f32x4 acc[4][2];
    #pragma unroll
    for (int i = 0; i < 4; ++i)
        #pragma unroll
        for (int j = 0; j < 2; ++j) acc[i][j] = (f32x4){0,0,0,0};

    for (int k0 = 0; k0 < KD; k0 += BK) {
        // stage A (already bf16): 128 rows x 32 bf16, 16B chunks
        #pragma unroll
        for (int r = 0; r < (BM * (BK / 8)) / 256; ++r) {
            int idx = r * 256 + tid;
            int row = idx >> 2, c = idx & 3;
            int rp = rowid[row];
            bf16x8 v = *(const bf16x8*)(Hin + (size_t)rp * KD + k0 + c * 8);
            *(bf16x8*)(As + row * LDA + c * 8) = v;
        }
        // stage W: 64 rows x 32 fp32 -> bf16
        #pragma unroll
        for (int r = 0; r < (BN * (BK / 4)) / 256; ++r) {
            int idx = r * 256 + tid;
            int n = idx >> 3, kq = idx & 7;
            size_t off = (size_t)(ntb * BN + n) * KD + k0 + kq * 4;
            *(bf16x4*)(Ws + n * LDA + kq * 4) = cvt4(*(const float4*)(wd + off));
        }
        __syncthreads();

        bf16x8 af[4], bf[2];
        #pragma unroll
        for (int mt = 0; mt < 4; ++mt)
            af[mt] = *(const bf16x8*)(As + (wm * 64 + mt * 16 + lrow) * LDA + quad * 8);
        #pragma unroll
        for (int nt = 0; nt < 2; ++nt)
            bf[nt] = *(const bf16x8*)(Ws + (wn * 32 + nt * 16 + lrow) * LDA + quad * 8);
        #pragma unroll
        for (int mt = 0; mt < 4; ++mt)
            #pragma unroll
            for (int nt = 0; nt < 2; ++nt)
                acc[mt][nt] = __builtin_amdgcn_mfma_f32_16x16x32_bf16(af[mt], bf[nt], acc[mt][nt], 0, 0, 0);
        __syncthreads();
    }

    #pragma unroll
    for (int mt = 0; mt < 4; ++mt)
        #pragma unroll
        for (int r = 0; r < 4; ++r) {
            int row_local = wm * 64 + mt * 16 + quad * 4 + r;
            int gm = mtb * BM + row_local;
            if (gm >= cnt) continue;
            int p = rowid[row_local];
            #pragma unroll
            for (int nt = 0; nt < 2; ++nt) {
                int col = ntb * BN + wn * 32 + nt * 16 + lrow;
                float val = acc[mt][nt][r];
                if (EXPERT) {
                    float wgt = topkw[p];
                    atomicAdd(&out[(size_t)(p >> 2) * HD + col], wgt * val);
                } else {
                    out[(size_t)p * HD + col] = val;
                }
            }
        }
}

extern "C" void kernel_launch(void* const* d_in, const int* in_sizes, int n_in,
                              void* d_out, int out_size, void* d_ws, size_t ws_size,
                              hipStream_t stream) {
    const float* hs  = (const float*)d_in[0];
    const float* rw  = (const float*)d_in[1];
    const float* rb  = (const float*)d_in[2];
    const float* gw  = (const float*)d_in[3];
    const float* uw  = (const float*)d_in[4];
    const float* dw  = (const float*)d_in[5];
    const float* sgw = (const float*)d_in[6];
    const float* suw = (const float*)d_in[7];
    const float* sdw = (const float*)d_in[8];
    float* out = (float*)d_out;

    // workspace layout
    char* ws = (char*)d_ws;
    int*    counts = (int*)ws;                                  // 128 B
    float*  topkw  = (float*)(ws + 128);                        // 32 KB
    int*    lists  = (int*)(ws + 128 + 32768);                  // 256 KB
    bf16_t* hbuf   = (bf16_t*)(ws + 128 + 32768 + 262144);      // max(8192*512, 2048*1024) bf16 = 8.4 MB

    zero_counts_kernel<<<1, 64, 0, stream>>>(counts);
    router_kernel<<<NT, 64, 0, stream>>>(hs, rw, rb, topkw, counts, lists);

    // shared expert: hsh = silu(x@sgw^T)*(x@suw^T); out = hsh@sdw^T (plain writes)
    gateup_mfma<false, SHI><<<dim3(1, NT / BM, SHI / BN), 256, 0, stream>>>(
        hs, sgw, suw, hbuf, nullptr, nullptr);
    down_mfma<false, SHI><<<dim3(1, NT / BM, HD / BN), 256, 0, stream>>>(
        hbuf, sdw, out, nullptr, nullptr, nullptr);

    // routed experts: h[p] = silu(x@gw_e^T)*(x@uw_e^T); out += w_p * h[p]@dw_e^T
    gateup_mfma<true, ID><<<dim3(NE, NT / BM, ID / BN), 256, 0, stream>>>(
        hs, gw, uw, hbuf, lists, counts);
    down_mfma<true, ID><<<dim3(NE, NT / BM, HD / BN), 256, 0, stream>>>(
        hbuf, dw, out, lists, counts, topkw);
}

// Round 3
// 418.436 us; speedup vs baseline: 2.9762x; 1.4738x over previous
//
#include <hip/hip_runtime.h>
#include <hip/hip_bf16.h>
#include <math.h>

// Problem constants
#define HD 1024     // hidden H
#define ID 512      // moe intermediate I
#define NE 32       // n experts
#define NT 2048     // tokens T = B*S
#define NG 4        // n_group
#define SHI 1024    // shared intermediate I*N_SHARED
#define SCALE 2.5f

// MFMA GEMM tile params
#define BM 128
#define BN 64
#define BK 32
#define LDA 40      // LDS row stride in bf16 (32 + 8 pad -> 80B rows)

typedef __bf16 bf16_t;
typedef __attribute__((ext_vector_type(8))) __bf16 bf16x8;
typedef __attribute__((ext_vector_type(4))) __bf16 bf16x4;
typedef __attribute__((ext_vector_type(4))) float f32x4;

// ---------------- router stage 1: logits GEMM + zero counts ----------------
// logits[t][e] = x[t] . rw[e]; fp32 throughout (bit-compatible with serial router)
// grid: NT/8 blocks of 256. thread: tslot = tid>>5 (8 tokens), ecol = tid&31.
#define LTOK 8
#define LKC 64
__global__ void __launch_bounds__(256) logits_kernel(
    const float* __restrict__ hs, const float* __restrict__ rw,
    float* __restrict__ logits, int* __restrict__ counts)
{
    if (blockIdx.x == 0 && threadIdx.x < NE) counts[threadIdx.x] = 0;

    __shared__ float Xs[LTOK][68];   // 68-stride: float4-aligned, conflict-free
    __shared__ float Ws[NE][65];     // 65-stride: bank = (e + k) % 32, conflict-free

    int tid = threadIdx.x;
    int t0 = blockIdx.x * LTOK;
    int tslot = tid >> 5, ecol = tid & 31;
    float acc = 0.f;

    for (int k0 = 0; k0 < HD; k0 += LKC) {
        // stage X: 8 tokens x 64 floats = 128 float4 (threads 0..127)
        if (tid < 128) {
            int row = tid >> 4, q = tid & 15;
            float4 v = *(const float4*)(hs + (size_t)(t0 + row) * HD + k0 + q * 4);
            *(float4*)(&Xs[row][q * 4]) = v;
        }
        // stage W: 32 experts x 64 floats = 2048 scalars, 8/thread
        #pragma unroll
        for (int i = 0; i < 8; ++i) {
            int idx = i * 256 + tid;
            int e = idx >> 6, kk = idx & 63;
            Ws[e][kk] = rw[(size_t)e * HD + k0 + kk];
        }
        __syncthreads();
        #pragma unroll 8
        for (int kk = 0; kk < LKC; ++kk)
            acc += Xs[tslot][kk] * Ws[ecol][kk];
        __syncthreads();
    }
    logits[(size_t)(t0 + tslot) * NE + ecol] = acc;
}

// ---------------- router stage 2: per-token top-k ----------------
// one thread per token; fully unrolled so arrays stay in registers
__global__ void __launch_bounds__(256) topk_kernel(
    const float* __restrict__ logits, const float* __restrict__ rb,
    float* __restrict__ topkw, int* __restrict__ counts, int* __restrict__ lists)
{
    int t = blockIdx.x * 256 + threadIdx.x;
    if (t >= NT) return;

    float scores[NE], sfc[NE], tmp[NE];
    #pragma unroll
    for (int e = 0; e < NE; ++e) {
        float l = logits[(size_t)t * NE + e];
        float s = 1.f / (1.f + __expf(-l));
        scores[e] = s;
        sfc[e] = s + rb[e];
    }
    // group scores = sum of top-2 per group of 8
    float gs[NG];
    #pragma unroll
    for (int g = 0; g < NG; ++g) {
        float m1 = -1e30f, m2 = -1e30f;
        #pragma unroll
        for (int j = 0; j < 8; ++j) {
            float v = sfc[g * 8 + j];
            if (v > m1) { m2 = m1; m1 = v; } else if (v > m2) m2 = v;
        }
        gs[g] = m1 + m2;
    }
    // top-2 groups, first-occurrence tie-break
    int g1 = 0;
    #pragma unroll
    for (int g = 1; g < NG; ++g) if (gs[g] > gs[g1]) g1 = g;
    int g2 = -1;
    #pragma unroll
    for (int g = 0; g < NG; ++g) {
        if (g == g1) continue;
        if (g2 < 0 || gs[g] > gs[g2]) g2 = g;
    }
    #pragma unroll
    for (int e = 0; e < NE; ++e) {
        int g = e >> 3;
        tmp[e] = (g == g1 || g == g2) ? sfc[e] : 0.0f;
    }
    int idx[4]; float wk[4]; float wsum = 0.f;
    #pragma unroll
    for (int k = 0; k < 4; ++k) {
        int best = 0; float bv = -1e30f;
        #pragma unroll
        for (int e = 0; e < NE; ++e) if (tmp[e] > bv) { bv = tmp[e]; best = e; }
        idx[k] = best; tmp[best] = -1e30f;
        wk[k] = scores[best]; wsum += wk[k];
    }
    float inv = SCALE / (wsum + 1e-20f);
    #pragma unroll
    for (int k = 0; k < 4; ++k) {
        int p = t * 4 + k;
        topkw[p] = wk[k] * inv;
        int e = idx[k];
        int pos = atomicAdd(&counts[e], 1);
        lists[e * NT + pos] = p;
    }
}

__device__ inline bf16x4 cvt4(float4 v) {
    bf16x4 r;
    r[0] = (__bf16)v.x; r[1] = (__bf16)v.y; r[2] = (__bf16)v.z; r[3] = (__bf16)v.w;
    return r;
}

// ---------------- fused gate/up + SwiGLU, bf16 MFMA ----------------
// X fp32 [tokens, HD]; Wg/Wu fp32 [(E,) ND, HD]; Hout bf16 [rows, ND]
// EXPERT: rows indexed by pair p from lists; else by token.
template<bool EXPERT, int ND>
__global__ void __launch_bounds__(256) gateup_mfma(
    const float* __restrict__ X, const float* __restrict__ Wg,
    const float* __restrict__ Wu, bf16_t* __restrict__ Hout,
    const int* __restrict__ lists, const int* __restrict__ counts)
{
    int e = 0, cnt = NT;
    const float* wg = Wg; const float* wu = Wu;
    if (EXPERT) {
        e = blockIdx.x; cnt = counts[e];
        wg = Wg + (size_t)e * ND * HD;
        wu = Wu + (size_t)e * ND * HD;
    }
    int mtb = blockIdx.y, ntb = blockIdx.z;
    if (mtb * BM >= cnt) return;

    __shared__ __align__(16) bf16_t As[BM * LDA];
    __shared__ __align__(16) bf16_t Bgs[BN * LDA];
    __shared__ __align__(16) bf16_t Bus[BN * LDA];
    __shared__ int rowid[BM];

    int tid = threadIdx.x;
    if (tid < BM) {
        int gm = mtb * BM + tid;
        int mm = gm < cnt ? gm : cnt - 1;
        rowid[tid] = EXPERT ? lists[e * NT + mm] : mm;
    }
    __syncthreads();

    int lane = tid & 63;
    int w = tid >> 6;
    int wm = w & 1, wn = w >> 1;
    int lrow = lane & 15, quad = lane >> 4;

    f32x4 accg[4][2], accu[4][2];
    #pragma unroll
    for (int i = 0; i < 4; ++i)
        #pragma unroll
        for (int j = 0; j < 2; ++j) { accg[i][j] = (f32x4){0,0,0,0}; accu[i][j] = (f32x4){0,0,0,0}; }

    for (int k0 = 0; k0 < HD; k0 += BK) {
        // stage A: 128 rows x 32 fp32 -> bf16
        #pragma unroll
        for (int r = 0; r < (BM * (BK / 4)) / 256; ++r) {
            int idx = r * 256 + tid;
            int row = idx >> 3, kq = idx & 7;
            int tok = EXPERT ? (rowid[row] >> 2) : rowid[row];
            float4 v = *(const float4*)(X + (size_t)tok * HD + k0 + kq * 4);
            *(bf16x4*)(As + row * LDA + kq * 4) = cvt4(v);
        }
        // stage Bg, Bu: 64 rows x 32 fp32 each
        #pragma unroll
        for (int r = 0; r < (BN * (BK / 4)) / 256; ++r) {
            int idx = r * 256 + tid;
            int n = idx >> 3, kq = idx & 7;
            size_t off = (size_t)(ntb * BN + n) * HD + k0 + kq * 4;
            *(bf16x4*)(Bgs + n * LDA + kq * 4) = cvt4(*(const float4*)(wg + off));
            *(bf16x4*)(Bus + n * LDA + kq * 4) = cvt4(*(const float4*)(wu + off));
        }
        __syncthreads();

        bf16x8 af[4], bg[2], bu[2];
        #pragma unroll
        for (int mt = 0; mt < 4; ++mt)
            af[mt] = *(const bf16x8*)(As + (wm * 64 + mt * 16 + lrow) * LDA + quad * 8);
        #pragma unroll
        for (int nt = 0; nt < 2; ++nt) {
            bg[nt] = *(const bf16x8*)(Bgs + (wn * 32 + nt * 16 + lrow) * LDA + quad * 8);
            bu[nt] = *(const bf16x8*)(Bus + (wn * 32 + nt * 16 + lrow) * LDA + quad * 8);
        }
        #pragma unroll
        for (int mt = 0; mt < 4; ++mt)
            #pragma unroll
            for (int nt = 0; nt < 2; ++nt) {
                accg[mt][nt] = __builtin_amdgcn_mfma_f32_16x16x32_bf16(af[mt], bg[nt], accg[mt][nt], 0, 0, 0);
                accu[mt][nt] = __builtin_amdgcn_mfma_f32_16x16x32_bf16(af[mt], bu[nt], accu[mt][nt], 0, 0, 0);
            }
        __syncthreads();
    }

    // epilogue: h = silu(g)*u, store bf16
    #pragma unroll
    for (int mt = 0; mt < 4; ++mt)
        #pragma unroll
        for (int r = 0; r < 4; ++r) {
            int row_local = wm * 64 + mt * 16 + quad * 4 + r;
            int gm = mtb * BM + row_local;
            if (gm >= cnt) continue;
            int p = rowid[row_local];
            #pragma unroll
            for (int nt = 0; nt < 2; ++nt) {
                int col = ntb * BN + wn * 32 + nt * 16 + lrow;
                float g = accg[mt][nt][r], u = accu[mt][nt][r];
                float h = (g / (1.f + __expf(-g))) * u;
                Hout[(size_t)p * ND + col] = (__bf16)h;
            }
        }
}

// ---------------- down projection, bf16 MFMA ----------------
// Hin bf16 [rows, KD]; Wd fp32 [(E,) HD, KD]; out fp32 [NT, HD]
// EXPERT: atomicAdd(w_p * val); else plain store (must run first).
template<bool EXPERT, int KD>
__global__ void __launch_bounds__(256) down_mfma(
    const bf16_t* __restrict__ Hin, const float* __restrict__ Wd,
    float* __restrict__ out, const int* __restrict__ lists,
    const int* __restrict__ counts, const float* __restrict__ topkw)
{
    int e = 0, cnt = NT;
    const float* wd = Wd;
    if (EXPERT) {
        e = blockIdx.x; cnt = counts[e];
        wd = Wd + (size_t)e * HD * KD;
    }
    int mtb = blockIdx.y, ntb = blockIdx.z;
    if (mtb * BM >= cnt) return;

    __shared__ __align__(16) bf16_t As[BM * LDA];
    __shared__ __align__(16) bf16_t Ws[BN * LDA];
    __shared__ int rowid[BM];

    int tid = threadIdx.x;
    if (tid < BM) {
        int gm = mtb * BM + tid;
        int mm = gm < cnt ? gm : cnt - 1;
        rowid[tid] = EXPERT ? lists[e * NT + mm] : mm;
    }
    __syncthreads();

    int lane = tid & 63;
    int w = tid >> 6;
    int wm = w & 1, wn = w >> 1;
    int lrow = lane & 15, quad = lane >> 4;

    f32x4 acc[4][2];
    #pragma unroll
    for (int i = 0; i < 4; ++i)
        #pragma unroll
        for (int j = 0; j < 2; ++j) acc[i][j] = (f32x4){0,0,0,0};

    for (int k0 = 0; k0 < KD; k0 += BK) {
        // stage A (already bf16): 128 rows x 32 bf16, 16B chunks
        #pragma unroll
        for (int r = 0; r < (BM * (BK / 8)) / 256; ++r) {
            int idx = r * 256 + tid;
            int row = idx >> 2, c = idx & 3;
            int rp = rowid[row];
            bf16x8 v = *(const bf16x8*)(Hin + (size_t)rp * KD + k0 + c * 8);
            *(bf16x8*)(As + row * LDA + c * 8) = v;
        }
        // stage W: 64 rows x 32 fp32 -> bf16
        #pragma unroll
        for (int r = 0; r < (BN * (BK / 4)) / 256; ++r) {
            int idx = r * 256 + tid;
            int n = idx >> 3, kq = idx & 7;
            size_t off = (size_t)(ntb * BN + n) * KD + k0 + kq * 4;
            *(bf16x4*)(Ws + n * LDA + kq * 4) = cvt4(*(const float4*)(wd + off));
        }
        __syncthreads();

        bf16x8 af[4], bf[2];
        #pragma unroll
        for (int mt = 0; mt < 4; ++mt)
            af[mt] = *(const bf16x8*)(As + (wm * 64 + mt * 16 + lrow) * LDA + quad * 8);
        #pragma unroll
        for (int nt = 0; nt < 2; ++nt)
            bf[nt] = *(const bf16x8*)(Ws + (wn * 32 + nt * 16 + lrow) * LDA + quad * 8);
        #pragma unroll
        for (int mt = 0; mt < 4; ++mt)
            #pragma unroll
            for (int nt = 0; nt < 2; ++nt)
                acc[mt][nt] = __builtin_amdgcn_mfma_f32_16x16x32_bf16(af[mt], bf[nt], acc[mt][nt], 0, 0, 0);
        __syncthreads();
    }

    #pragma unroll
    for (int mt = 0; mt < 4; ++mt)
        #pragma unroll
        for (int r = 0; r < 4; ++r) {
            int row_local = wm * 64 + mt * 16 + quad * 4 + r;
            int gm = mtb * BM + row_local;
            if (gm >= cnt) continue;
            int p = rowid[row_local];
            #pragma unroll
            for (int nt = 0; nt < 2; ++nt) {
                int col = ntb * BN + wn * 32 + nt * 16 + lrow;
                float val = acc[mt][nt][r];
                if (EXPERT) {
                    float wgt = topkw[p];
                    atomicAdd(&out[(size_t)(p >> 2) * HD + col], wgt * val);
                } else {
                    out[(size_t)p * HD + col] = val;
                }
            }
        }
}

extern "C" void kernel_launch(void* const* d_in, const int* in_sizes, int n_in,
                              void* d_out, int out_size, void* d_ws, size_t ws_size,
                              hipStream_t stream) {
    const float* hs  = (const float*)d_in[0];
    const float* rw  = (const float*)d_in[1];
    const float* rb  = (const float*)d_in[2];
    const float* gw  = (const float*)d_in[3];
    const float* uw  = (const float*)d_in[4];
    const float* dw  = (const float*)d_in[5];
    const float* sgw = (const float*)d_in[6];
    const float* suw = (const float*)d_in[7];
    const float* sdw = (const float*)d_in[8];
    float* out = (float*)d_out;

    // workspace layout
    char* ws = (char*)d_ws;
    int*    counts = (int*)ws;                                  // 128 B
    float*  topkw  = (float*)(ws + 128);                        // 32 KB
    int*    lists  = (int*)(ws + 128 + 32768);                  // 256 KB
    float*  logits = (float*)(ws + 128 + 32768 + 262144);       // 2048*32*4 = 256 KB
    bf16_t* hbuf   = (bf16_t*)(ws + 128 + 32768 + 262144 + 262144);  // 8.4 MB

    // router: logits GEMM (also zeroes counts), then per-token top-k
    logits_kernel<<<NT / LTOK, 256, 0, stream>>>(hs, rw, logits, counts);
    topk_kernel<<<NT / 256, 256, 0, stream>>>(logits, rb, topkw, counts, lists);

    // shared expert: hsh = silu(x@sgw^T)*(x@suw^T); out = hsh@sdw^T (plain writes)
    gateup_mfma<false, SHI><<<dim3(1, NT / BM, SHI / BN), 256, 0, stream>>>(
        hs, sgw, suw, hbuf, nullptr, nullptr);
    down_mfma<false, SHI><<<dim3(1, NT / BM, HD / BN), 256, 0, stream>>>(
        hbuf, sdw, out, nullptr, nullptr, nullptr);

    // routed experts: h[p] = silu(x@gw_e^T)*(x@uw_e^T); out += w_p * h[p]@dw_e^T
    gateup_mfma<true, ID><<<dim3(NE, NT / BM, ID / BN), 256, 0, stream>>>(
        hs, gw, uw, hbuf, lists, counts);
    down_mfma<true, ID><<<dim3(NE, NT / BM, HD / BN), 256, 0, stream>>>(
        hbuf, dw, out, lists, counts, topkw);
}

// Round 4
// 411.613 us; speedup vs baseline: 3.0255x; 1.0166x over previous
//
#include <hip/hip_runtime.h>
#include <hip/hip_bf16.h>
#include <math.h>

// Problem constants
#define HD 1024     // hidden H
#define ID 512      // moe intermediate I
#define NE 32       // n experts
#define NT 2048     // tokens T = B*S
#define NG 4        // n_group
#define SHI 1024    // shared intermediate I*N_SHARED
#define SCALE 2.5f

// MFMA GEMM tile params
#define BN 64
#define BK 32
#define LDA 40      // LDS row stride in bf16 (32 + 8 pad -> 80B rows)

typedef __bf16 bf16_t;
typedef __attribute__((ext_vector_type(8))) __bf16 bf16x8;
typedef __attribute__((ext_vector_type(4))) __bf16 bf16x4;
typedef __attribute__((ext_vector_type(4))) float f32x4;

// ---------------- router stage 1: logits GEMM + zero counts ----------------
#define LTOK 8
#define LKC 64
__global__ void __launch_bounds__(256) logits_kernel(
    const float* __restrict__ hs, const float* __restrict__ rw,
    float* __restrict__ logits, int* __restrict__ counts)
{
    if (blockIdx.x == 0 && threadIdx.x < NE) counts[threadIdx.x] = 0;

    __shared__ float Xs[LTOK][68];
    __shared__ float Ws[NE][65];

    int tid = threadIdx.x;
    int t0 = blockIdx.x * LTOK;
    int tslot = tid >> 5, ecol = tid & 31;
    float acc = 0.f;

    for (int k0 = 0; k0 < HD; k0 += LKC) {
        if (tid < 128) {
            int row = tid >> 4, q = tid & 15;
            float4 v = *(const float4*)(hs + (size_t)(t0 + row) * HD + k0 + q * 4);
            *(float4*)(&Xs[row][q * 4]) = v;
        }
        #pragma unroll
        for (int i = 0; i < 8; ++i) {
            int idx = i * 256 + tid;
            int e = idx >> 6, kk = idx & 63;
            Ws[e][kk] = rw[(size_t)e * HD + k0 + kk];
        }
        __syncthreads();
        #pragma unroll 8
        for (int kk = 0; kk < LKC; ++kk)
            acc += Xs[tslot][kk] * Ws[ecol][kk];
        __syncthreads();
    }
    logits[(size_t)(t0 + tslot) * NE + ecol] = acc;
}

// ---------------- router stage 2: per-token top-k ----------------
__global__ void __launch_bounds__(256) topk_kernel(
    const float* __restrict__ logits, const float* __restrict__ rb,
    float* __restrict__ topkw, int* __restrict__ counts, int* __restrict__ lists)
{
    int t = blockIdx.x * 256 + threadIdx.x;
    if (t >= NT) return;

    float scores[NE], sfc[NE], tmp[NE];
    #pragma unroll
    for (int e = 0; e < NE; ++e) {
        float l = logits[(size_t)t * NE + e];
        float s = 1.f / (1.f + __expf(-l));
        scores[e] = s;
        sfc[e] = s + rb[e];
    }
    float gs[NG];
    #pragma unroll
    for (int g = 0; g < NG; ++g) {
        float m1 = -1e30f, m2 = -1e30f;
        #pragma unroll
        for (int j = 0; j < 8; ++j) {
            float v = sfc[g * 8 + j];
            if (v > m1) { m2 = m1; m1 = v; } else if (v > m2) m2 = v;
        }
        gs[g] = m1 + m2;
    }
    int g1 = 0;
    #pragma unroll
    for (int g = 1; g < NG; ++g) if (gs[g] > gs[g1]) g1 = g;
    int g2 = -1;
    #pragma unroll
    for (int g = 0; g < NG; ++g) {
        if (g == g1) continue;
        if (g2 < 0 || gs[g] > gs[g2]) g2 = g;
    }
    #pragma unroll
    for (int e = 0; e < NE; ++e) {
        int g = e >> 3;
        tmp[e] = (g == g1 || g == g2) ? sfc[e] : 0.0f;
    }
    int idx[4]; float wk[4]; float wsum = 0.f;
    #pragma unroll
    for (int k = 0; k < 4; ++k) {
        int best = 0; float bv = -1e30f;
        #pragma unroll
        for (int e = 0; e < NE; ++e) if (tmp[e] > bv) { bv = tmp[e]; best = e; }
        idx[k] = best; tmp[best] = -1e30f;
        wk[k] = scores[best]; wsum += wk[k];
    }
    float inv = SCALE / (wsum + 1e-20f);
    #pragma unroll
    for (int k = 0; k < 4; ++k) {
        int p = t * 4 + k;
        topkw[p] = wk[k] * inv;
        int e = idx[k];
        int pos = atomicAdd(&counts[e], 1);
        lists[e * NT + pos] = p;
    }
}

__device__ inline bf16x4 cvt4(float4 v) {
    bf16x4 r;
    r[0] = (__bf16)v.x; r[1] = (__bf16)v.y; r[2] = (__bf16)v.z; r[3] = (__bf16)v.w;
    return r;
}

// ---------------- fused gate/up + SwiGLU, bf16 MFMA, VGPR-prefetch pipeline ----------------
// X fp32 [tokens, HD]; Wg/Wu fp32 [(E,) ND, HD]; Hout bf16 [rows, ND]
template<bool EXPERT, int ND, int BMT>
__global__ void __launch_bounds__(256) gateup_mfma(
    const float* __restrict__ X, const float* __restrict__ Wg,
    const float* __restrict__ Wu, bf16_t* __restrict__ Hout,
    const int* __restrict__ lists, const int* __restrict__ counts)
{
    int e = 0, cnt = NT;
    const float* wg = Wg; const float* wu = Wu;
    if (EXPERT) {
        e = blockIdx.x; cnt = counts[e];
        wg = Wg + (size_t)e * ND * HD;
        wu = Wu + (size_t)e * ND * HD;
    }
    int mtb = blockIdx.y, ntb = blockIdx.z;
    if (mtb * BMT >= cnt) return;

    __shared__ __align__(16) bf16_t As[BMT * LDA];
    __shared__ __align__(16) bf16_t Bgs[BN * LDA];
    __shared__ __align__(16) bf16_t Bus[BN * LDA];
    __shared__ int rowid[BMT];

    int tid = threadIdx.x;
    if (tid < BMT) {
        int gm = mtb * BMT + tid;
        int mm = gm < cnt ? gm : cnt - 1;
        rowid[tid] = EXPERT ? lists[e * NT + mm] : mm;
    }
    __syncthreads();

    constexpr int AR = (BMT * BK) / (256 * 4);  // float4 per thread for A
    constexpr int BR = (BN * BK) / (256 * 4);   // float4 per thread per B tensor
    constexpr int MT = BMT / 32;                // m-tiles per wave

    int lane = tid & 63;
    int w = tid >> 6;
    int wm = w & 1, wn = w >> 1;
    int lrow = lane & 15, quad = lane >> 4;

    f32x4 accg[MT][2], accu[MT][2];
    #pragma unroll
    for (int i = 0; i < MT; ++i)
        #pragma unroll
        for (int j = 0; j < 2; ++j) { accg[i][j] = (f32x4){0,0,0,0}; accu[i][j] = (f32x4){0,0,0,0}; }

    float4 pa[AR], pbg[BR], pbu[BR];

    // prologue: load tile 0 into registers
    #pragma unroll
    for (int r = 0; r < AR; ++r) {
        int idx = r * 256 + tid;
        int row = idx >> 3, kq = idx & 7;
        int tok = EXPERT ? (rowid[row] >> 2) : rowid[row];
        pa[r] = *(const float4*)(X + (size_t)tok * HD + kq * 4);
    }
    #pragma unroll
    for (int r = 0; r < BR; ++r) {
        int idx = r * 256 + tid;
        int n = idx >> 3, kq = idx & 7;
        size_t off = (size_t)(ntb * BN + n) * HD + kq * 4;
        pbg[r] = *(const float4*)(wg + off);
        pbu[r] = *(const float4*)(wu + off);
    }

    for (int k0 = 0; k0 < HD; k0 += BK) {
        // commit prefetched tile k to LDS
        #pragma unroll
        for (int r = 0; r < AR; ++r) {
            int idx = r * 256 + tid;
            int row = idx >> 3, kq = idx & 7;
            *(bf16x4*)(As + row * LDA + kq * 4) = cvt4(pa[r]);
        }
        #pragma unroll
        for (int r = 0; r < BR; ++r) {
            int idx = r * 256 + tid;
            int n = idx >> 3, kq = idx & 7;
            *(bf16x4*)(Bgs + n * LDA + kq * 4) = cvt4(pbg[r]);
            *(bf16x4*)(Bus + n * LDA + kq * 4) = cvt4(pbu[r]);
        }
        __syncthreads();

        // issue global loads for tile k+1 (overlap with compute below)
        int k1 = k0 + BK;
        if (k1 < HD) {
            #pragma unroll
            for (int r = 0; r < AR; ++r) {
                int idx = r * 256 + tid;
                int row = idx >> 3, kq = idx & 7;
                int tok = EXPERT ? (rowid[row] >> 2) : rowid[row];
                pa[r] = *(const float4*)(X + (size_t)tok * HD + k1 + kq * 4);
            }
            #pragma unroll
            for (int r = 0; r < BR; ++r) {
                int idx = r * 256 + tid;
                int n = idx >> 3, kq = idx & 7;
                size_t off = (size_t)(ntb * BN + n) * HD + k1 + kq * 4;
                pbg[r] = *(const float4*)(wg + off);
                pbu[r] = *(const float4*)(wu + off);
            }
        }

        bf16x8 af[MT], bg[2], bu[2];
        #pragma unroll
        for (int mt = 0; mt < MT; ++mt)
            af[mt] = *(const bf16x8*)(As + (wm * (BMT / 2) + mt * 16 + lrow) * LDA + quad * 8);
        #pragma unroll
        for (int nt = 0; nt < 2; ++nt) {
            bg[nt] = *(const bf16x8*)(Bgs + (wn * 32 + nt * 16 + lrow) * LDA + quad * 8);
            bu[nt] = *(const bf16x8*)(Bus + (wn * 32 + nt * 16 + lrow) * LDA + quad * 8);
        }
        #pragma unroll
        for (int mt = 0; mt < MT; ++mt)
            #pragma unroll
            for (int nt = 0; nt < 2; ++nt) {
                accg[mt][nt] = __builtin_amdgcn_mfma_f32_16x16x32_bf16(af[mt], bg[nt], accg[mt][nt], 0, 0, 0);
                accu[mt][nt] = __builtin_amdgcn_mfma_f32_16x16x32_bf16(af[mt], bu[nt], accu[mt][nt], 0, 0, 0);
            }
        __syncthreads();
    }

    // epilogue: h = silu(g)*u, store bf16
    #pragma unroll
    for (int mt = 0; mt < MT; ++mt)
        #pragma unroll
        for (int r = 0; r < 4; ++r) {
            int row_local = wm * (BMT / 2) + mt * 16 + quad * 4 + r;
            int gm = mtb * BMT + row_local;
            if (gm >= cnt) continue;
            int p = rowid[row_local];
            #pragma unroll
            for (int nt = 0; nt < 2; ++nt) {
                int col = ntb * BN + wn * 32 + nt * 16 + lrow;
                float g = accg[mt][nt][r], u = accu[mt][nt][r];
                float h = (g / (1.f + __expf(-g))) * u;
                Hout[(size_t)p * ND + col] = (__bf16)h;
            }
        }
}

// ---------------- down projection, bf16 MFMA, VGPR-prefetch pipeline ----------------
// Hin bf16 [rows, KD]; Wd fp32 [(E,) HD, KD]; out fp32 [NT, HD]
template<bool EXPERT, int KD, int BMT>
__global__ void __launch_bounds__(256) down_mfma(
    const bf16_t* __restrict__ Hin, const float* __restrict__ Wd,
    float* __restrict__ out, const int* __restrict__ lists,
    const int* __restrict__ counts, const float* __restrict__ topkw)
{
    int e = 0, cnt = NT;
    const float* wd = Wd;
    if (EXPERT) {
        e = blockIdx.x; cnt = counts[e];
        wd = Wd + (size_t)e * HD * KD;
    }
    int mtb = blockIdx.y, ntb = blockIdx.z;
    if (mtb * BMT >= cnt) return;

    __shared__ __align__(16) bf16_t As[BMT * LDA];
    __shared__ __align__(16) bf16_t Ws[BN * LDA];
    __shared__ int rowid[BMT];

    int tid = threadIdx.x;
    if (tid < BMT) {
        int gm = mtb * BMT + tid;
        int mm = gm < cnt ? gm : cnt - 1;
        rowid[tid] = EXPERT ? lists[e * NT + mm] : mm;
    }
    __syncthreads();

    constexpr int ARH = (BMT * BK / 8) / 256;   // bf16x8 per thread for A
    constexpr int BR = (BN * BK) / (256 * 4);   // float4 per thread for W
    constexpr int MT = BMT / 32;

    int lane = tid & 63;
    int w = tid >> 6;
    int wm = w & 1, wn = w >> 1;
    int lrow = lane & 15, quad = lane >> 4;

    f32x4 acc[MT][2];
    #pragma unroll
    for (int i = 0; i < MT; ++i)
        #pragma unroll
        for (int j = 0; j < 2; ++j) acc[i][j] = (f32x4){0,0,0,0};

    bf16x8 pa[ARH];
    float4 pw[BR];

    #pragma unroll
    for (int r = 0; r < ARH; ++r) {
        int idx = r * 256 + tid;
        int row = idx >> 2, c = idx & 3;
        pa[r] = *(const bf16x8*)(Hin + (size_t)rowid[row] * KD + c * 8);
    }
    #pragma unroll
    for (int r = 0; r < BR; ++r) {
        int idx = r * 256 + tid;
        int n = idx >> 3, kq = idx & 7;
        pw[r] = *(const float4*)(wd + (size_t)(ntb * BN + n) * KD + kq * 4);
    }

    for (int k0 = 0; k0 < KD; k0 += BK) {
        #pragma unroll
        for (int r = 0; r < ARH; ++r) {
            int idx = r * 256 + tid;
            int row = idx >> 2, c = idx & 3;
            *(bf16x8*)(As + row * LDA + c * 8) = pa[r];
        }
        #pragma unroll
        for (int r = 0; r < BR; ++r) {
            int idx = r * 256 + tid;
            int n = idx >> 3, kq = idx & 7;
            *(bf16x4*)(Ws + n * LDA + kq * 4) = cvt4(pw[r]);
        }
        __syncthreads();

        int k1 = k0 + BK;
        if (k1 < KD) {
            #pragma unroll
            for (int r = 0; r < ARH; ++r) {
                int idx = r * 256 + tid;
                int row = idx >> 2, c = idx & 3;
                pa[r] = *(const bf16x8*)(Hin + (size_t)rowid[row] * KD + k1 + c * 8);
            }
            #pragma unroll
            for (int r = 0; r < BR; ++r) {
                int idx = r * 256 + tid;
                int n = idx >> 3, kq = idx & 7;
                pw[r] = *(const float4*)(wd + (size_t)(ntb * BN + n) * KD + k1 + kq * 4);
            }
        }

        bf16x8 af[MT], bf[2];
        #pragma unroll
        for (int mt = 0; mt < MT; ++mt)
            af[mt] = *(const bf16x8*)(As + (wm * (BMT / 2) + mt * 16 + lrow) * LDA + quad * 8);
        #pragma unroll
        for (int nt = 0; nt < 2; ++nt)
            bf[nt] = *(const bf16x8*)(Ws + (wn * 32 + nt * 16 + lrow) * LDA + quad * 8);
        #pragma unroll
        for (int mt = 0; mt < MT; ++mt)
            #pragma unroll
            for (int nt = 0; nt < 2; ++nt)
                acc[mt][nt] = __builtin_amdgcn_mfma_f32_16x16x32_bf16(af[mt], bf[nt], acc[mt][nt], 0, 0, 0);
        __syncthreads();
    }

    #pragma unroll
    for (int mt = 0; mt < MT; ++mt)
        #pragma unroll
        for (int r = 0; r < 4; ++r) {
            int row_local = wm * (BMT / 2) + mt * 16 + quad * 4 + r;
            int gm = mtb * BMT + row_local;
            if (gm >= cnt) continue;
            int p = rowid[row_local];
            #pragma unroll
            for (int nt = 0; nt < 2; ++nt) {
                int col = ntb * BN + wn * 32 + nt * 16 + lrow;
                float val = acc[mt][nt][r];
                if (EXPERT) {
                    float wgt = topkw[p];
                    atomicAdd(&out[(size_t)(p >> 2) * HD + col], wgt * val);
                } else {
                    out[(size_t)p * HD + col] = val;
                }
            }
        }
}

extern "C" void kernel_launch(void* const* d_in, const int* in_sizes, int n_in,
                              void* d_out, int out_size, void* d_ws, size_t ws_size,
                              hipStream_t stream) {
    const float* hs  = (const float*)d_in[0];
    const float* rw  = (const float*)d_in[1];
    const float* rb  = (const float*)d_in[2];
    const float* gw  = (const float*)d_in[3];
    const float* uw  = (const float*)d_in[4];
    const float* dw  = (const float*)d_in[5];
    const float* sgw = (const float*)d_in[6];
    const float* suw = (const float*)d_in[7];
    const float* sdw = (const float*)d_in[8];
    float* out = (float*)d_out;

    // workspace layout
    char* ws = (char*)d_ws;
    int*    counts = (int*)ws;                                  // 128 B
    float*  topkw  = (float*)(ws + 128);                        // 32 KB
    int*    lists  = (int*)(ws + 128 + 32768);                  // 256 KB
    float*  logits = (float*)(ws + 128 + 32768 + 262144);       // 256 KB
    bf16_t* hbuf   = (bf16_t*)(ws + 128 + 32768 + 262144 + 262144);  // 8.4 MB

    // router
    logits_kernel<<<NT / LTOK, 256, 0, stream>>>(hs, rw, logits, counts);
    topk_kernel<<<NT / 256, 256, 0, stream>>>(logits, rb, topkw, counts, lists);

    // shared expert (BM=64 tiles for 2 blocks/CU)
    gateup_mfma<false, SHI, 64><<<dim3(1, NT / 64, SHI / BN), 256, 0, stream>>>(
        hs, sgw, suw, hbuf, nullptr, nullptr);
    down_mfma<false, SHI, 64><<<dim3(1, NT / 64, HD / BN), 256, 0, stream>>>(
        hbuf, sdw, out, nullptr, nullptr, nullptr);

    // routed experts (BM=128)
    gateup_mfma<true, ID, 128><<<dim3(NE, NT / 128, ID / BN), 256, 0, stream>>>(
        hs, gw, uw, hbuf, lists, counts);
    down_mfma<true, ID, 128><<<dim3(NE, NT / 128, HD / BN), 256, 0, stream>>>(
        hbuf, dw, out, lists, counts, topkw);
}